// Round 2
// baseline (314.746 us; speedup 1.0000x reference)
//
#include <hip/hip_runtime.h>
#include <math.h>

#define NS 96
#define SM1 95
#define NC 32
#define REPS 1e-10f

// Kernel 1: per-ray alpha + transmittance scan + weights. One ray per
// 128-thread block (2 waves -> 16 blocks/CU resident).
__global__ __launch_bounds__(128) void raymarch_scan(
    const float* __restrict__ densities,  // [rays, 96]
    const float* __restrict__ depths,     // [rays, 96]
    float* __restrict__ out_depth,        // [rays] (unclipped, nan->inf)
    float* __restrict__ out_w,            // [rays, 95]
    float* __restrict__ out_alpha,        // [rays, 95]
    float* __restrict__ out_wbg,          // [rays]
    float* __restrict__ ws_coeff,         // [rays, 96]
    float* __restrict__ ws_d0,            // [rays]
    float* __restrict__ ws_d1)            // [rays]
{
    const int ray = blockIdx.x;
    const int t = threadIdx.x;

    __shared__ float s_dep[NS];
    __shared__ float s_den[NS];
    __shared__ float s_alpha[SM1];
    __shared__ float s_scan[SM1];   // oma, scanned in place
    __shared__ float s_w[SM1];
    __shared__ float s_a[128];
    __shared__ float s_b[128];

    const float* dep = depths + (size_t)ray * NS;
    const float* den = densities + (size_t)ray * NS;

    if (t < NS) {
        s_dep[t] = dep[t];
        s_den[t] = den[t];
    }
    __syncthreads();

    if (t < SM1) {
        float dm = 0.5f * (s_den[t] + s_den[t + 1]) - 1.0f;
        // jax.nn.softplus: max(x,0) + log1p(exp(-|x|))
        float sp = fmaxf(dm, 0.0f) + log1pf(expf(-fabsf(dm)));
        float dd = sp * (s_dep[t + 1] - s_dep[t]);
        float a = 1.0f - expf(-dd);
        s_alpha[t] = a;
        s_scan[t] = 1.0f - a + REPS;
        out_alpha[(size_t)ray * SM1 + t] = a;
    }
    __syncthreads();

    // Inclusive multiplicative Hillis-Steele scan over s_scan[0..94].
    #pragma unroll
    for (int off = 1; off < SM1; off <<= 1) {
        float x = 1.0f;
        if (t >= off && t < SM1) x = s_scan[t - off];
        __syncthreads();
        if (t >= off && t < SM1) s_scan[t] *= x;
        __syncthreads();
    }

    float w = 0.0f;
    if (t < SM1) {
        float T = (t == 0) ? 1.0f : s_scan[t - 1];
        w = s_alpha[t] * T;
        s_w[t] = w;
        out_w[(size_t)ray * SM1 + t] = w;
    }
    s_a[t] = w;
    s_b[t] = (t < SM1) ? w * 0.5f * (s_dep[t] + s_dep[t + 1]) : 0.0f;
    __syncthreads();

    #pragma unroll
    for (int off = 64; off > 0; off >>= 1) {
        if (t < off) {
            s_a[t] += s_a[t + off];
            s_b[t] += s_b[t + off];
        }
        __syncthreads();
    }

    if (t == 0) {
        out_wbg[ray] = s_scan[SM1 - 1];
        float cd = s_b[0] / s_a[0];
        if (cd != cd) cd = __builtin_inff();  // NaN -> inf; clip in finalize
        out_depth[ray] = cd;
        ws_d0[ray] = s_dep[0];
        ws_d1[ray] = s_dep[NS - 1];
    }
    if (t < NS) {
        float wprev = (t >= 1)  ? s_w[t - 1] : 0.0f;
        float wcur  = (t < SM1) ? s_w[t]     : 0.0f;
        ws_coeff[(size_t)ray * NS + t] = 0.5f * (wprev + wcur);
    }
}

// Kernel 2: pure streaming color composite. One ray per 256-thread block.
// composite_rgb[c] = sum_s coeff[s] * colors[s][c]
__global__ __launch_bounds__(256) void raymarch_color(
    const float* __restrict__ colors,     // [rays, 96, 32]
    const float* __restrict__ ws_coeff,   // [rays, 96]
    float* __restrict__ out_rgb)          // [rays, 32]
{
    const int ray = blockIdx.x;
    const int t = threadIdx.x;

    __shared__ float s_coeff[NS];
    __shared__ float s_red[256 * 4];

    // Issue the heavy HBM loads first.
    const float4* col4 = (const float4*)(colors + (size_t)ray * NS * NC);
    float4 v0 = col4[t];
    float4 v1 = col4[256 + t];
    float4 v2 = col4[512 + t];

    if (t < NS) s_coeff[t] = ws_coeff[(size_t)ray * NS + t];
    __syncthreads();

    // float4 index i covers sample s = i>>3, channels 4*(i&7)..4*(i&7)+3.
    float c0 = s_coeff[t >> 3];
    float c1 = s_coeff[(256 + t) >> 3];
    float c2 = s_coeff[(512 + t) >> 3];
    float4 acc;
    acc.x = fmaf(c0, v0.x, fmaf(c1, v1.x, c2 * v2.x));
    acc.y = fmaf(c0, v0.y, fmaf(c1, v1.y, c2 * v2.y));
    acc.z = fmaf(c0, v0.z, fmaf(c1, v1.z, c2 * v2.z));
    acc.w = fmaf(c0, v0.w, fmaf(c1, v1.w, c2 * v2.w));

    s_red[t * 4 + 0] = acc.x;
    s_red[t * 4 + 1] = acc.y;
    s_red[t * 4 + 2] = acc.z;
    s_red[t * 4 + 3] = acc.w;
    __syncthreads();

    if (t < NC) {
        // channel t; partials at s_red[m*32 + t], m = 0..31 (stride-1 across
        // threads -> conflict-free)
        float sum = 0.0f;
        #pragma unroll
        for (int m = 0; m < 32; ++m) {
            sum += s_red[m * 32 + t];
        }
        out_rgb[(size_t)ray * NC + t] = 2.0f * sum - 1.0f;
    }
}

// Grid-wide min/max of depths (sorted along S -> endpoints suffice), clip.
__global__ __launch_bounds__(256) void raymarch_finalize(
    const float* __restrict__ ws_d0,
    const float* __restrict__ ws_d1,
    float* __restrict__ out_depth,
    int rays)
{
    __shared__ float s_mn[256];
    __shared__ float s_mx[256];
    const int tid = threadIdx.x;

    float mn = __builtin_inff();
    float mx = -__builtin_inff();
    for (int r = tid; r < rays; r += 256) {
        mn = fminf(mn, ws_d0[r]);
        mx = fmaxf(mx, ws_d1[r]);
    }
    s_mn[tid] = mn;
    s_mx[tid] = mx;
    __syncthreads();
    for (int off = 128; off > 0; off >>= 1) {
        if (tid < off) {
            s_mn[tid] = fminf(s_mn[tid], s_mn[tid + off]);
            s_mx[tid] = fmaxf(s_mx[tid], s_mx[tid + off]);
        }
        __syncthreads();
    }
    const float dmin = s_mn[0];
    const float dmax = s_mx[0];

    const int r = blockIdx.x * 256 + tid;
    if (r < rays) {
        float cd = out_depth[r];
        cd = fminf(fmaxf(cd, dmin), dmax);  // clip(inf) -> dmax, matches jnp
        out_depth[r] = cd;
    }
}

extern "C" void kernel_launch(void* const* d_in, const int* in_sizes, int n_in,
                              void* d_out, int out_size, void* d_ws, size_t ws_size,
                              hipStream_t stream) {
    const float* colors    = (const float*)d_in[0];
    const float* densities = (const float*)d_in[1];
    const float* depths    = (const float*)d_in[2];

    const int rays = in_sizes[2] / NS;  // B*R = 16384

    float* out = (float*)d_out;
    float* out_rgb   = out;                                   // rays*32
    float* out_depth = out_rgb + (size_t)rays * NC;           // rays
    float* out_w     = out_depth + rays;                      // rays*95
    float* out_alpha = out_w + (size_t)rays * SM1;            // rays*95
    float* out_wbg   = out_alpha + (size_t)rays * SM1;        // rays

    float* ws       = (float*)d_ws;
    float* ws_d0    = ws;                                     // rays
    float* ws_d1    = ws + rays;                              // rays
    float* ws_coeff = ws + 2 * (size_t)rays;                  // rays*96

    raymarch_scan<<<rays, 128, 0, stream>>>(
        densities, depths,
        out_depth, out_w, out_alpha, out_wbg, ws_coeff, ws_d0, ws_d1);

    raymarch_color<<<rays, 256, 0, stream>>>(colors, ws_coeff, out_rgb);

    raymarch_finalize<<<(rays + 255) / 256, 256, 0, stream>>>(
        ws_d0, ws_d1, out_depth, rays);
}